// Round 6
// baseline (1411.012 us; speedup 1.0000x reference)
//
#include <hip/hip_runtime.h>
#include <cstdint>
#include <cstddef>

typedef short short8_t __attribute__((ext_vector_type(8)));
typedef float float4_t __attribute__((ext_vector_type(4)));

#define NRG 32   // row-groups (64 batch rows each); 8 col-blocks per rg

// Fragment-packed weights (rebuilt from d_in every call).
__device__ __align__(16) unsigned short g_W[1024 * 384];
__device__ __align__(16) unsigned short g_Weff[1024 * 256];
__device__ __align__(16) unsigned short g_Wlin[128 * 256];
__device__ float g_bias[1024];   // b_ih + b_hh
__device__ float g_beff[1024];   // bias + Wih @ b_lin
__device__ float g_blin[128];
// h exchange: [rg][parity][row 0..63][dim 0..255] bf16, system-scope (sc0 sc1) only.
__device__ __align__(16) unsigned short g_hx[NRG][2][64][256];
__device__ int g_flag[NRG][4][8];   // [rg][wave][col-block] = last step+1 written

__device__ __forceinline__ unsigned short f2bf_rn(float f) {
    union { float f; unsigned int u; } v; v.f = f;
    unsigned int u = v.u;
    return (unsigned short)((u + 0x7FFFu + ((u >> 16) & 1u)) >> 16);
}
__device__ __forceinline__ float sigm(float x) { return 1.0f / (1.0f + __expf(-x)); }
__device__ __forceinline__ float tanh_fast(float x) { return 2.0f / (1.0f + __expf(-2.0f * x)) - 1.0f; }

__global__ void prep_kernel(const float* __restrict__ w_ih, const float* __restrict__ w_hh,
                            const float* __restrict__ b_ih, const float* __restrict__ b_hh,
                            const float* __restrict__ w_lin, const float* __restrict__ b_lin) {
    int idx = blockIdx.x * blockDim.x + threadIdx.x;
    int stride = gridDim.x * blockDim.x;
    for (int i = idx; i < 49152; i += stride) {   // 768 frags * 64 lanes
        int f = i >> 6, l = i & 63;
        int kt = f % 12, rest = f / 12;
        int s = rest & 3, wvv = (rest >> 2) & 3, g = rest >> 4;
        int n = g * 256 + wvv * 64 + s * 16 + (l & 15);
        int k0 = kt * 32 + (l >> 4) * 8;
        unsigned short* dst = g_W + f * 512 + l * 8;
#pragma unroll
        for (int j = 0; j < 8; ++j) {
            int k = k0 + j;
            float v = (k < 128) ? w_ih[n * 128 + k] : w_hh[n * 256 + (k - 128)];
            dst[j] = f2bf_rn(v);
        }
    }
    for (int i = idx; i < 4096; i += stride) {    // wlin: 64 frags * 64 lanes
        int f = i >> 6, l = i & 63;
        int kt = f & 7, wss = f >> 3;
        int s = wss & 1, wvv = wss >> 1;
        int n = wvv * 32 + s * 16 + (l & 15);
        int k0 = kt * 32 + (l >> 4) * 8;
        unsigned short* dst = g_Wlin + f * 512 + l * 8;
#pragma unroll
        for (int j = 0; j < 8; ++j)
            dst[j] = f2bf_rn(w_lin[n * 256 + k0 + j]);
    }
    for (int i = idx; i < 1024; i += stride) g_bias[i] = b_ih[i] + b_hh[i];
    for (int i = idx; i < 128; i += stride) g_blin[i] = b_lin[i];
    for (int i = idx; i < NRG * 32; i += stride) ((int*)g_flag)[i] = 0;
}

// Weff[n][k] = Whh[n][k] + sum_p Wih[n][p]*wlin[p][k]; beff = bias + Wih@blin
__global__ void prep2_kernel(const float* __restrict__ w_ih, const float* __restrict__ w_hh,
                             const float* __restrict__ w_lin, const float* __restrict__ b_ih,
                             const float* __restrict__ b_hh, const float* __restrict__ b_lin) {
    int i = blockIdx.x * 256 + threadIdx.x;       // grid 1024*256 = 262144
    {
        int e = i & 511, f = i >> 9;
        int l = e >> 3, j = e & 7;
        int kt2 = f & 7, rest = f >> 3;
        int s = rest & 3, w = (rest >> 2) & 3, g = rest >> 4;
        int n = g * 256 + w * 64 + s * 16 + (l & 15);
        int k = kt2 * 32 + (l >> 4) * 8 + j;
        float acc = w_hh[n * 256 + k];
#pragma unroll 4
        for (int p = 0; p < 128; ++p)
            acc += w_ih[n * 128 + p] * w_lin[p * 256 + k];
        g_Weff[f * 512 + e] = f2bf_rn(acc);
    }
    if (i < 1024) {
        float acc = b_ih[i] + b_hh[i];
        for (int p = 0; p < 128; ++p)
            acc += w_ih[i * 128 + p] * b_lin[p];
        g_beff[i] = acc;
    }
}

#define WAITCNT0 do { asm volatile("s_waitcnt vmcnt(0)" ::: "memory"); \
                      __builtin_amdgcn_sched_barrier(0); } while (0)

#define POLL(RG, WANT) do { \
    __builtin_amdgcn_sched_barrier(0); \
    const int* fp_ = &g_flag[RG][wv][l & 7]; \
    int fv_, guard_ = 0; \
    do { \
        asm volatile("global_load_dword %0, %1, off sc0 sc1\n\ts_waitcnt vmcnt(0)" \
                     : "=v"(fv_) : "v"(fp_) : "memory"); \
    } while (!__all(fv_ >= (WANT)) && ++guard_ < (1 << 18)); \
    __builtin_amdgcn_sched_barrier(0); \
} while (0)

#define ISSUE_HA(HA, RG, PAR) do { \
    const char* hb_ = (const char*)&g_hx[RG][PAR][wv * 16 + l15][lg * 8]; \
    _Pragma("unroll") \
    for (int kt_ = 0; kt_ < 8; ++kt_) \
        asm volatile("global_load_dwordx4 %0, %1, off sc0 sc1" \
                     : "=v"(HA[kt_]) : "v"(hb_ + kt_ * 64) : "memory"); \
} while (0)

#define ISSUE_XF(XF, XROW, TT) do { \
    const char* xp_ = (const char*)((XROW) + (size_t)(TT) * 128); \
    _Pragma("unroll") \
    for (int q_ = 0; q_ < 8; ++q_) \
        asm volatile("global_load_dwordx4 %0, %1, off" \
                     : "=v"(XF[q_]) : "v"(xp_ + ((q_ >> 1) * 128 + (q_ & 1) * 16)) : "memory"); \
} while (0)

#define CONVERT_XA(XF) do { \
    _Pragma("unroll") \
    for (int kt_ = 0; kt_ < 4; ++kt_) { \
        short8_t vv_; \
        vv_[0] = (short)f2bf_rn(XF[2*kt_][0]); vv_[1] = (short)f2bf_rn(XF[2*kt_][1]); \
        vv_[2] = (short)f2bf_rn(XF[2*kt_][2]); vv_[3] = (short)f2bf_rn(XF[2*kt_][3]); \
        vv_[4] = (short)f2bf_rn(XF[2*kt_+1][0]); vv_[5] = (short)f2bf_rn(XF[2*kt_+1][1]); \
        vv_[6] = (short)f2bf_rn(XF[2*kt_+1][2]); vv_[7] = (short)f2bf_rn(XF[2*kt_+1][3]); \
        xa[kt_] = vv_; \
    } \
} while (0)

#define XPART() do { \
    _Pragma("unroll") \
    for (int kt_ = 0; kt_ < 4; ++kt_) \
        _Pragma("unroll") \
        for (int g_ = 0; g_ < 4; ++g_) \
            _Pragma("unroll") \
            for (int s2_ = 0; s2_ < 2; ++s2_) { \
                const short8_t wf_ = *(const short8_t*)&gw[((g_*2+s2_)*12+kt_)*512 + l*8]; \
                acc[g_][s2_] = __builtin_amdgcn_mfma_f32_16x16x32_bf16(xa[kt_], wf_, acc[g_][s2_], 0, 0, 0); \
            } \
} while (0)

#define HPART_ENC(HA) do { \
    _Pragma("unroll") \
    for (int kt_ = 4; kt_ < 12; ++kt_) \
        _Pragma("unroll") \
        for (int g_ = 0; g_ < 4; ++g_) \
            _Pragma("unroll") \
            for (int s2_ = 0; s2_ < 2; ++s2_) { \
                const short8_t wf_ = *(const short8_t*)&gw[((g_*2+s2_)*12+kt_)*512 + l*8]; \
                acc[g_][s2_] = __builtin_amdgcn_mfma_f32_16x16x32_bf16(HA[kt_-4], wf_, acc[g_][s2_], 0, 0, 0); \
            } \
} while (0)

#define HPART_AR(HA) do { \
    _Pragma("unroll") \
    for (int kt_ = 0; kt_ < 8; ++kt_) \
        _Pragma("unroll") \
        for (int g_ = 0; g_ < 4; ++g_) \
            _Pragma("unroll") \
            for (int s2_ = 0; s2_ < 2; ++s2_) { \
                const short8_t wf_ = *(const short8_t*)&gw[((g_*2+s2_)*8+kt_)*512 + l*8]; \
                acc[g_][s2_] = __builtin_amdgcn_mfma_f32_16x16x32_bf16(HA[kt_], wf_, acc[g_][s2_], 0, 0, 0); \
            } \
} while (0)

#define POINTWISE_STORE(RG, CST, PAR, FLAGVAL) do { \
    char* tbw_ = (char*)&tb[wv][0]; \
    _Pragma("unroll") \
    for (int s2_ = 0; s2_ < 2; ++s2_) \
        _Pragma("unroll") \
        for (int r_ = 0; r_ < 4; ++r_) { \
            float ip_ = acc[0][s2_][r_], fp2_ = acc[1][s2_][r_]; \
            float gp_ = acc[2][s2_][r_], op_ = acc[3][s2_][r_]; \
            float cn_ = sigm(fp2_) * CST[s2_][r_] + sigm(ip_) * tanh_fast(gp_); \
            CST[s2_][r_] = cn_; \
            float hv_ = sigm(op_) * tanh_fast(cn_); \
            int m_ = lg * 4 + r_; \
            int boff_ = (m_ * 64 + (s2_ * 16 + l15) * 2) ^ (lg << 4); \
            *(unsigned short*)(tbw_ + boff_) = f2bf_rn(hv_); \
        } \
    int roff_ = (l15 * 64 + (lg << 4)) ^ ((l15 >> 2) << 4); \
    short8_t hv8_ = *(const short8_t*)(tbw_ + roff_); \
    char* dst_ = (char*)&g_hx[RG][PAR][wv * 16 + l15][c * 32 + lg * 8]; \
    asm volatile("global_store_dwordx4 %0, %1, off sc0 sc1" :: "v"(dst_), "v"(hv8_) : "memory"); \
    WAITCNT0; \
    if (l == 0) { \
        int* fw_ = &g_flag[RG][wv][c]; \
        int nv_ = (FLAGVAL); \
        asm volatile("global_store_dword %0, %1, off sc0 sc1" :: "v"(fw_), "v"(nv_) : "memory"); \
    } \
} while (0)

#define PRED(HA, RG, KO) do { \
    float4_t pacc_ = {blin_r, blin_r, blin_r, blin_r}; \
    _Pragma("unroll") \
    for (int kt_ = 0; kt_ < 8; ++kt_) { \
        const short8_t wf_ = *(const short8_t*)&wl_sh[kt_ * 512 + l * 8]; \
        pacc_ = __builtin_amdgcn_mfma_f32_16x16x32_bf16(HA[kt_], wf_, pacc_, 0, 0, 0); \
    } \
    float* orow_ = out + ((size_t)((RG) * 64 + wv * 16 + lg * 4) * 32 + (KO)) * 128 + c * 16 + l15; \
    _Pragma("unroll") \
    for (int r_ = 0; r_ < 4; ++r_) \
        orow_[(size_t)r_ * 32 * 128] = pacc_[r_]; \
} while (0)

// 128 blocks = 16 super-rg x 8 c. Each wave runs TWO independent 16-row chains
// (rgA = 2*srg, rgB = 2*srg+1) ping-ponged so exchange latency of one chain
// hides under compute of the other. Exchange protocol identical to R3 (proven).
__global__ void __launch_bounds__(256, 1) lstm_persist(const float* __restrict__ inp,
                                                       float* __restrict__ out) {
    __shared__ __align__(16) unsigned short gw[96 * 512];     // 96 KiB weights
    __shared__ __align__(16) unsigned short wl_sh[8 * 512];   // 8 KiB wlin slice
    __shared__ __align__(16) unsigned short tb[4][512];       // 1 KiB/wave transpose buf

    const int tid = threadIdx.x;
    const int wv = tid >> 6, l = tid & 63, l15 = l & 15, lg = l >> 4;
    const int c = blockIdx.x >> 4, srg = blockIdx.x & 15;
    const int rgA = 2 * srg, rgB = 2 * srg + 1;

    for (int i = tid; i < 96 * 64; i += 256) {
        int lf = i >> 6, ch = i & 63;
        int kt = lf % 12, gs = lf / 12;
        int s2 = gs & 1, g = gs >> 1;
        int gf = ((g * 4 + (c >> 1)) * 4 + 2 * (c & 1) + s2) * 12 + kt;
        *(uint4*)&gw[lf * 512 + ch * 8] = *(const uint4*)&g_W[gf * 512 + ch * 8];
    }
    for (int i = tid; i < 8 * 64; i += 256) {
        int lf = i >> 6, ch = i & 63;
        *(uint4*)&wl_sh[lf * 512 + ch * 8] = *(const uint4*)&g_Wlin[(c * 8 + lf) * 512 + ch * 8];
    }
    float biasr[4][2], beffr[4][2];
#pragma unroll
    for (int g = 0; g < 4; ++g)
#pragma unroll
        for (int s2 = 0; s2 < 2; ++s2) {
            biasr[g][s2] = g_bias[g * 256 + c * 32 + s2 * 16 + l15];
            beffr[g][s2] = g_beff[g * 256 + c * 32 + s2 * 16 + l15];
        }
    const float blin_r = g_blin[c * 16 + l15];
    __syncthreads();

    short8_t haA[8], haB[8], xa[4];
    float4_t xfA[8], xfB[8];
    float cA[2][4], cB[2][4];
#pragma unroll
    for (int s2 = 0; s2 < 2; ++s2)
#pragma unroll
        for (int r = 0; r < 4; ++r) { cA[s2][r] = 0.0f; cB[s2][r] = 0.0f; }

    const float* xrowA = inp + (size_t)(rgA * 64 + wv * 16 + l15) * 8192 + lg * 8;
    const float* xrowB = inp + (size_t)(rgB * 64 + wv * 16 + l15) * 8192 + lg * 8;
    ISSUE_XF(xfA, xrowA, 0);
    ISSUE_XF(xfB, xrowB, 0);

    for (int t = 0; t <= 95; ++t) {
        if (t == 64) {   // one-time: overwrite gw slots 0..63 with Weff slice
            __syncthreads();
            for (int i = tid; i < 64 * 64; i += 256) {
                int lf = i >> 6, ch = i & 63;
                int kt2 = lf & 7, gs = lf >> 3;
                int s2 = gs & 1, g = gs >> 1;
                int gf = ((g * 4 + (c >> 1)) * 4 + 2 * (c & 1) + s2) * 8 + kt2;
                *(uint4*)&gw[lf * 512 + ch * 8] = *(const uint4*)&g_Weff[gf * 512 + ch * 8];
            }
            __syncthreads();
        }
        const bool enc = (t < 64);

        // ---- seg1: poll chain-B peers for h_B(t-1), issue its loads ----
        if (t > 0) {
            POLL(rgB, t);
            ISSUE_HA(haB, rgB, (t - 1) & 1);
        } else {
            WAITCNT0;   // drain prologue xf
        }

        // ---- chain A: compute step t (uses haA = h_A(t-1), drained by seg1 poll) ----
        if (t < 95) {
            float4_t acc[4][2];
#pragma unroll
            for (int g = 0; g < 4; ++g)
#pragma unroll
                for (int s2 = 0; s2 < 2; ++s2) {
                    float b = enc ? biasr[g][s2] : beffr[g][s2];
                    acc[g][s2] = (float4_t){b, b, b, b};
                }
            if (enc) { CONVERT_XA(xfA); XPART(); }
            if (t > 0) { if (enc) HPART_ENC(haA); else HPART_AR(haA); }
            POINTWISE_STORE(rgA, cA, t & 1, t + 1);
        }
        if (t >= 64) PRED(haA, rgA, t - 64);   // uses h_A(t-1), before haA overwrite

        // ---- poll chain-A peers for h_A(t), issue next loads (long flight) ----
        if (t < 95) {
            POLL(rgA, t + 1);
            ISSUE_HA(haA, rgA, t & 1);
            if (t <= 62) ISSUE_XF(xfA, xrowA, t + 1);
        }

        // ---- chain B: compute step t (haB drained by seg-pollA's vmcnt(0)) ----
        if (t < 95) {
            float4_t acc[4][2];
#pragma unroll
            for (int g = 0; g < 4; ++g)
#pragma unroll
                for (int s2 = 0; s2 < 2; ++s2) {
                    float b = enc ? biasr[g][s2] : beffr[g][s2];
                    acc[g][s2] = (float4_t){b, b, b, b};
                }
            if (enc) { CONVERT_XA(xfB); XPART(); }
            if (t > 0) { if (enc) HPART_ENC(haB); else HPART_AR(haB); }
            POINTWISE_STORE(rgB, cB, t & 1, t + 1);
            if (t <= 62) ISSUE_XF(xfB, xrowB, t + 1);
        }
        if (t >= 64) {
            if (t == 95) WAITCNT0;             // haB(94) drain (stores skipped at t=95)
            PRED(haB, rgB, t - 64);
        }
    }
}

extern "C" void kernel_launch(void* const* d_in, const int* in_sizes, int n_in,
                              void* d_out, int out_size, void* d_ws, size_t ws_size,
                              hipStream_t stream) {
    const float* inp   = (const float*)d_in[0];
    const float* w_ih  = (const float*)d_in[1];
    const float* w_hh  = (const float*)d_in[2];
    const float* b_ih  = (const float*)d_in[3];
    const float* b_hh  = (const float*)d_in[4];
    const float* w_lin = (const float*)d_in[5];
    const float* b_lin = (const float*)d_in[6];
    (void)in_sizes; (void)n_in; (void)d_ws; (void)ws_size; (void)out_size;

    prep_kernel<<<128, 256, 0, stream>>>(w_ih, w_hh, b_ih, b_hh, w_lin, b_lin);
    prep2_kernel<<<1024, 256, 0, stream>>>(w_ih, w_hh, w_lin, b_ih, b_hh, b_lin);
    lstm_persist<<<128, 256, 0, stream>>>(inp, (float*)d_out);
}

// Round 7
// 617.244 us; speedup vs baseline: 2.2860x; 2.2860x over previous
//
#include <hip/hip_runtime.h>
#include <cstdint>
#include <cstddef>

typedef short short8_t __attribute__((ext_vector_type(8)));
typedef float float4_t __attribute__((ext_vector_type(4)));
typedef int   int4_t   __attribute__((ext_vector_type(4)));

#define NRG 32   // row-groups (64 batch rows each); 8 col-blocks per rg

// Fragment-packed weights (rebuilt from d_in every call).
__device__ __align__(16) unsigned short g_W[1024 * 384];
__device__ __align__(16) unsigned short g_Weff[1024 * 256];
__device__ __align__(16) unsigned short g_Wlin[128 * 256];
__device__ float g_bias[1024];   // b_ih + b_hh
__device__ float g_beff[1024];   // bias + Wih @ b_lin
__device__ float g_blin[128];
// Sentinel-tagged h exchange ring: [rg][slot 0..3][row 0..63][dim 0..255] bf16.
// 0xFFFF bf16 (NaN) is impossible for |h|<1, so readers poll the DATA directly:
// sentinel -> not yet written; anything else -> fresh h. One round trip, no flags.
__device__ __align__(16) unsigned short g_hs[NRG][4][64][256];

__device__ __forceinline__ unsigned short f2bf_rn(float f) {
    union { float f; unsigned int u; } v; v.f = f;
    unsigned int u = v.u;
    return (unsigned short)((u + 0x7FFFu + ((u >> 16) & 1u)) >> 16);
}
__device__ __forceinline__ float sigm(float x) { return 1.0f / (1.0f + __expf(-x)); }
__device__ __forceinline__ float tanh_fast(float x) { return 2.0f / (1.0f + __expf(-2.0f * x)) - 1.0f; }

__global__ void prep_kernel(const float* __restrict__ w_ih, const float* __restrict__ w_hh,
                            const float* __restrict__ b_ih, const float* __restrict__ b_hh,
                            const float* __restrict__ w_lin, const float* __restrict__ b_lin) {
    int idx = blockIdx.x * blockDim.x + threadIdx.x;
    int stride = gridDim.x * blockDim.x;
    for (int i = idx; i < 49152; i += stride) {   // 768 frags * 64 lanes
        int f = i >> 6, l = i & 63;
        int kt = f % 12, rest = f / 12;
        int s = rest & 3, wvv = (rest >> 2) & 3, g = rest >> 4;
        int n = g * 256 + wvv * 64 + s * 16 + (l & 15);
        int k0 = kt * 32 + (l >> 4) * 8;
        unsigned short* dst = g_W + f * 512 + l * 8;
#pragma unroll
        for (int j = 0; j < 8; ++j) {
            int k = k0 + j;
            float v = (k < 128) ? w_ih[n * 128 + k] : w_hh[n * 256 + (k - 128)];
            dst[j] = f2bf_rn(v);
        }
    }
    for (int i = idx; i < 4096; i += stride) {    // wlin: 64 frags * 64 lanes
        int f = i >> 6, l = i & 63;
        int kt = f & 7, wss = f >> 3;
        int s = wss & 1, wvv = wss >> 1;
        int n = wvv * 32 + s * 16 + (l & 15);
        int k0 = kt * 32 + (l >> 4) * 8;
        unsigned short* dst = g_Wlin + f * 512 + l * 8;
#pragma unroll
        for (int j = 0; j < 8; ++j)
            dst[j] = f2bf_rn(w_lin[n * 256 + k0 + j]);
    }
    for (int i = idx; i < 1024; i += stride) g_bias[i] = b_ih[i] + b_hh[i];
    for (int i = idx; i < 128; i += stride) g_blin[i] = b_lin[i];
    // sentinel-fill the exchange ring (kernel-end writeback makes it visible)
    int* hs = (int*)g_hs;
    for (int i = idx; i < (int)(sizeof(g_hs) / 4); i += stride) hs[i] = -1;
}

// Weff[n][k] = Whh[n][k] + sum_p Wih[n][p]*wlin[p][k]; beff = bias + Wih@blin
__global__ void prep2_kernel(const float* __restrict__ w_ih, const float* __restrict__ w_hh,
                             const float* __restrict__ w_lin, const float* __restrict__ b_ih,
                             const float* __restrict__ b_hh, const float* __restrict__ b_lin) {
    int i = blockIdx.x * 256 + threadIdx.x;       // grid 1024*256 = 262144
    {
        int e = i & 511, f = i >> 9;
        int l = e >> 3, j = e & 7;
        int kt2 = f & 7, rest = f >> 3;
        int s = rest & 3, w = (rest >> 2) & 3, g = rest >> 4;
        int n = g * 256 + w * 64 + s * 16 + (l & 15);
        int k = kt2 * 32 + (l >> 4) * 8 + j;
        float acc = w_hh[n * 256 + k];
#pragma unroll 4
        for (int p = 0; p < 128; ++p)
            acc += w_ih[n * 128 + p] * w_lin[p * 256 + k];
        g_Weff[f * 512 + e] = f2bf_rn(acc);
    }
    if (i < 1024) {
        float acc = b_ih[i] + b_hh[i];
        for (int p = 0; p < 128; ++p)
            acc += w_ih[i * 128 + p] * b_lin[p];
        g_beff[i] = acc;
    }
}

#define WAITCNT0 do { asm volatile("s_waitcnt vmcnt(0)" ::: "memory"); \
                      __builtin_amdgcn_sched_barrier(0); } while (0)

// Poll the h data itself: re-load all 8 fragments until no lane sees sentinel.
#define POLLDATA(SLOT) do { \
    const char* hb_ = (const char*)&g_hs[rg][SLOT][wv * 16 + l15][lg * 8]; \
    int guard_ = 0, ok_; \
    do { \
        _Pragma("unroll") \
        for (int kt_ = 0; kt_ < 8; ++kt_) \
            asm volatile("global_load_dwordx4 %0, %1, off sc0 sc1" \
                         : "=v"(ha[kt_]) : "v"(hb_ + kt_ * 64) : "memory"); \
        asm volatile("s_waitcnt vmcnt(0)" ::: "memory"); \
        __builtin_amdgcn_sched_barrier(0); \
        ok_ = 1; \
        _Pragma("unroll") \
        for (int kt_ = 0; kt_ < 8; ++kt_) { \
            int4_t iv_ = __builtin_bit_cast(int4_t, ha[kt_]); \
            ok_ &= (iv_[0] != -1) & (iv_[1] != -1) & (iv_[2] != -1) & (iv_[3] != -1); \
        } \
    } while (!__all(ok_) && ++guard_ < (1 << 15)); \
    __builtin_amdgcn_sched_barrier(0); \
} while (0)

// Pre-clear this block's region of a future slot to sentinel (ordered before the
// eventual data store by the intervening poll's vmcnt(0) drain).
#define CLEARSLOT(SLOT) do { \
    char* cz_ = (char*)&g_hs[rg][SLOT][wv * 16 + l15][c * 32 + lg * 8]; \
    int4_t sv_; sv_[0] = -1; sv_[1] = -1; sv_[2] = -1; sv_[3] = -1; \
    asm volatile("global_store_dwordx4 %0, %1, off sc0 sc1" :: "v"(cz_), "v"(sv_) : "memory"); \
} while (0)

#define ISSUE_XF(XF, XROW, TT) do { \
    const char* xp_ = (const char*)((XROW) + (size_t)(TT) * 128); \
    _Pragma("unroll") \
    for (int q_ = 0; q_ < 8; ++q_) \
        asm volatile("global_load_dwordx4 %0, %1, off" \
                     : "=v"(XF[q_]) : "v"(xp_ + ((q_ >> 1) * 128 + (q_ & 1) * 16)) : "memory"); \
} while (0)

#define CONVERT_XA(XF) do { \
    _Pragma("unroll") \
    for (int kt_ = 0; kt_ < 4; ++kt_) { \
        short8_t vv_; \
        vv_[0] = (short)f2bf_rn(XF[2*kt_][0]); vv_[1] = (short)f2bf_rn(XF[2*kt_][1]); \
        vv_[2] = (short)f2bf_rn(XF[2*kt_][2]); vv_[3] = (short)f2bf_rn(XF[2*kt_][3]); \
        vv_[4] = (short)f2bf_rn(XF[2*kt_+1][0]); vv_[5] = (short)f2bf_rn(XF[2*kt_+1][1]); \
        vv_[6] = (short)f2bf_rn(XF[2*kt_+1][2]); vv_[7] = (short)f2bf_rn(XF[2*kt_+1][3]); \
        xa[kt_] = vv_; \
    } \
} while (0)

#define XPART() do { \
    _Pragma("unroll") \
    for (int kt_ = 0; kt_ < 4; ++kt_) \
        _Pragma("unroll") \
        for (int g_ = 0; g_ < 4; ++g_) \
            _Pragma("unroll") \
            for (int s2_ = 0; s2_ < 2; ++s2_) { \
                const short8_t wf_ = *(const short8_t*)&gw[((g_*2+s2_)*12+kt_)*512 + l*8]; \
                acc[g_][s2_] = __builtin_amdgcn_mfma_f32_16x16x32_bf16(xa[kt_], wf_, acc[g_][s2_], 0, 0, 0); \
            } \
} while (0)

#define HPART_ENC() do { \
    _Pragma("unroll") \
    for (int kt_ = 4; kt_ < 12; ++kt_) \
        _Pragma("unroll") \
        for (int g_ = 0; g_ < 4; ++g_) \
            _Pragma("unroll") \
            for (int s2_ = 0; s2_ < 2; ++s2_) { \
                const short8_t wf_ = *(const short8_t*)&gw[((g_*2+s2_)*12+kt_)*512 + l*8]; \
                acc[g_][s2_] = __builtin_amdgcn_mfma_f32_16x16x32_bf16(ha[kt_-4], wf_, acc[g_][s2_], 0, 0, 0); \
            } \
} while (0)

#define HPART_AR() do { \
    _Pragma("unroll") \
    for (int kt_ = 0; kt_ < 8; ++kt_) \
        _Pragma("unroll") \
        for (int g_ = 0; g_ < 4; ++g_) \
            _Pragma("unroll") \
            for (int s2_ = 0; s2_ < 2; ++s2_) { \
                const short8_t wf_ = *(const short8_t*)&gw[((g_*2+s2_)*8+kt_)*512 + l*8]; \
                acc[g_][s2_] = __builtin_amdgcn_mfma_f32_16x16x32_bf16(ha[kt_], wf_, acc[g_][s2_], 0, 0, 0); \
            } \
} while (0)

// pointwise + transpose + fire-and-forget data store (no drain, no flag)
#define POINTWISE_STORE(SLOT) do { \
    char* tbw_ = (char*)&tb[wv][0]; \
    _Pragma("unroll") \
    for (int s2_ = 0; s2_ < 2; ++s2_) \
        _Pragma("unroll") \
        for (int r_ = 0; r_ < 4; ++r_) { \
            float ip_ = acc[0][s2_][r_], fp2_ = acc[1][s2_][r_]; \
            float gp_ = acc[2][s2_][r_], op_ = acc[3][s2_][r_]; \
            float cn_ = sigm(fp2_) * c_st[s2_][r_] + sigm(ip_) * tanh_fast(gp_); \
            c_st[s2_][r_] = cn_; \
            float hv_ = sigm(op_) * tanh_fast(cn_); \
            int m_ = lg * 4 + r_; \
            int boff_ = (m_ * 64 + (s2_ * 16 + l15) * 2) ^ (lg << 4); \
            *(unsigned short*)(tbw_ + boff_) = f2bf_rn(hv_); \
        } \
    int roff_ = (l15 * 64 + (lg << 4)) ^ ((l15 >> 2) << 4); \
    short8_t hv8_ = *(const short8_t*)(tbw_ + roff_); \
    char* dst_ = (char*)&g_hs[rg][SLOT][wv * 16 + l15][c * 32 + lg * 8]; \
    asm volatile("global_store_dwordx4 %0, %1, off sc0 sc1" :: "v"(dst_), "v"(hv8_) : "memory"); \
} while (0)

#define PRED(KO) do { \
    float4_t pacc_ = {blin_r, blin_r, blin_r, blin_r}; \
    _Pragma("unroll") \
    for (int kt_ = 0; kt_ < 8; ++kt_) { \
        const short8_t wf_ = *(const short8_t*)&wl_sh[kt_ * 512 + l * 8]; \
        pacc_ = __builtin_amdgcn_mfma_f32_16x16x32_bf16(ha[kt_], wf_, pacc_, 0, 0, 0); \
    } \
    float* orow_ = out + ((size_t)(rg * 64 + wv * 16 + lg * 4) * 32 + (KO)) * 128 + c * 16 + l15; \
    _Pragma("unroll") \
    for (int r_ = 0; r_ < 4; ++r_) \
        orow_[(size_t)r_ * 32 * 128] = pacc_[r_]; \
} while (0)

// 256 blocks = 32 rg x 8 c. Block (rg,c): 64 rows, h/gate dims [c*32,c*32+32).
// Per-step exchange: sentinel-polled data ring, single round trip discovery.
__global__ void __launch_bounds__(256, 1) lstm_persist(const float* __restrict__ inp,
                                                       float* __restrict__ out) {
    __shared__ __align__(16) unsigned short gw[96 * 512];     // 96 KiB weights
    __shared__ __align__(16) unsigned short wl_sh[8 * 512];   // 8 KiB wlin slice
    __shared__ __align__(16) unsigned short tb[4][512];       // 1 KiB/wave transpose buf

    const int tid = threadIdx.x;
    const int wv = tid >> 6, l = tid & 63, l15 = l & 15, lg = l >> 4;
    const int c = blockIdx.x >> 5, rg = blockIdx.x & 31;

    for (int i = tid; i < 96 * 64; i += 256) {
        int lf = i >> 6, ch = i & 63;
        int kt = lf % 12, gs = lf / 12;
        int s2 = gs & 1, g = gs >> 1;
        int gf = ((g * 4 + (c >> 1)) * 4 + 2 * (c & 1) + s2) * 12 + kt;
        *(uint4*)&gw[lf * 512 + ch * 8] = *(const uint4*)&g_W[gf * 512 + ch * 8];
    }
    for (int i = tid; i < 8 * 64; i += 256) {
        int lf = i >> 6, ch = i & 63;
        *(uint4*)&wl_sh[lf * 512 + ch * 8] = *(const uint4*)&g_Wlin[(c * 8 + lf) * 512 + ch * 8];
    }
    float biasr[4][2], beffr[4][2];
#pragma unroll
    for (int g = 0; g < 4; ++g)
#pragma unroll
        for (int s2 = 0; s2 < 2; ++s2) {
            biasr[g][s2] = g_bias[g * 256 + c * 32 + s2 * 16 + l15];
            beffr[g][s2] = g_beff[g * 256 + c * 32 + s2 * 16 + l15];
        }
    const float blin_r = g_blin[c * 16 + l15];
    __syncthreads();

    short8_t ha[8], xa[4];
    float4_t xf[8];
    float c_st[2][4];
#pragma unroll
    for (int s2 = 0; s2 < 2; ++s2)
#pragma unroll
        for (int r = 0; r < 4; ++r) c_st[s2][r] = 0.0f;

    const float* xrow = inp + (size_t)(rg * 64 + wv * 16 + l15) * 8192 + lg * 8;
    ISSUE_XF(xf, xrow, 0);

    for (int t = 0; t <= 95; ++t) {
        if (t == 64) {   // one-time: overwrite gw slots 0..63 with Weff slice
            __syncthreads();
            for (int i = tid; i < 64 * 64; i += 256) {
                int lf = i >> 6, ch = i & 63;
                int kt2 = lf & 7, gs = lf >> 3;
                int s2 = gs & 1, g = gs >> 1;
                int gf = ((g * 4 + (c >> 1)) * 4 + 2 * (c & 1) + s2) * 8 + kt2;
                *(uint4*)&gw[lf * 512 + ch * 8] = *(const uint4*)&g_Weff[gf * 512 + ch * 8];
            }
            __syncthreads();
        }
        const bool enc = (t < 64);

        // sentinel pre-clear of the slot this block will write at step t+1
        if (t <= 93) CLEARSLOT((t + 1) & 3);

        float4_t acc[4][2];
        if (t < 95) {
#pragma unroll
            for (int g = 0; g < 4; ++g)
#pragma unroll
                for (int s2 = 0; s2 < 2; ++s2) {
                    float b = enc ? biasr[g][s2] : beffr[g][s2];
                    acc[g][s2] = (float4_t){b, b, b, b};
                }
        }

        // acquire h(t-1): poll data ring (single round trip; also drains clear+xf)
        if (t > 0) POLLDATA((t - 1) & 3);
        else WAITCNT0;

        if (enc) {
            CONVERT_XA(xf);
            XPART();
            if (t <= 62) ISSUE_XF(xf, xrow, t + 1);   // flight hides under h-part+store
        }

        if (t < 95) {
            if (t > 0) { if (enc) HPART_ENC(); else HPART_AR(); }
            POINTWISE_STORE(t & 3);
        }

        if (t >= 64) PRED(t - 64);   // uses ha = h(t-1), off the critical path
    }
}

extern "C" void kernel_launch(void* const* d_in, const int* in_sizes, int n_in,
                              void* d_out, int out_size, void* d_ws, size_t ws_size,
                              hipStream_t stream) {
    const float* inp   = (const float*)d_in[0];
    const float* w_ih  = (const float*)d_in[1];
    const float* w_hh  = (const float*)d_in[2];
    const float* b_ih  = (const float*)d_in[3];
    const float* b_hh  = (const float*)d_in[4];
    const float* w_lin = (const float*)d_in[5];
    const float* b_lin = (const float*)d_in[6];
    (void)in_sizes; (void)n_in; (void)d_ws; (void)ws_size; (void)out_size;

    prep_kernel<<<128, 256, 0, stream>>>(w_ih, w_hh, b_ih, b_hh, w_lin, b_lin);
    prep2_kernel<<<1024, 256, 0, stream>>>(w_ih, w_hh, w_lin, b_ih, b_hh, b_lin);
    lstm_persist<<<256, 256, 0, stream>>>(inp, (float*)d_out);
}